// Round 18
// baseline (328.372 us; speedup 1.0000x reference)
//
#include <hip/hip_runtime.h>
#include <hip/hip_bf16.h>

typedef __attribute__((ext_vector_type(8))) short short8;
typedef __attribute__((ext_vector_type(4))) float f32x4;
typedef __attribute__((ext_vector_type(2))) float f32x2;
typedef __attribute__((ext_vector_type(4))) unsigned short us4;

__device__ __forceinline__ ushort f2bf(float f) {
    unsigned u = __float_as_uint(f);
    u += 0x7FFFu + ((u >> 16) & 1u);
    return (ushort)(u >> 16);
}
__device__ __forceinline__ float bf2f(ushort h) {
    return __uint_as_float(((unsigned)h) << 16);
}
__device__ __forceinline__ float lrelu(float e) { return (e >= 0.f) ? e : 0.2f * e; }
__device__ __forceinline__ unsigned char f2fp8(float v) {
    return (unsigned char)(__builtin_amdgcn_cvt_pk_fp8_f32(v, v, 0, false) & 0xFF);
}
__device__ __forceinline__ void gload16(const void* g, void* l) {
    __builtin_amdgcn_global_load_lds(
        (const __attribute__((address_space(1))) unsigned int*)g,
        (__attribute__((address_space(3))) unsigned int*)l, 16, 0, 0);
}

// ---------------- CSR scans ----------------
__global__ void k_scanA(const int* __restrict__ deg, int* __restrict__ bsum, int n) {
    __shared__ int sd[256];
    int t = blockIdx.x * 256 + threadIdx.x;
    sd[threadIdx.x] = (t < n) ? deg[t] + 1 : 0;
    __syncthreads();
    for (int off = 128; off > 0; off >>= 1) {
        if (threadIdx.x < off) sd[threadIdx.x] += sd[threadIdx.x + off];
        __syncthreads();
    }
    if (threadIdx.x == 0) bsum[blockIdx.x] = sd[0];
}
__global__ void k_scanC(const int* __restrict__ deg, const int* __restrict__ bsum,
                        int* __restrict__ rowptr, int* __restrict__ cursor,
                        int n, int etot, int nb) {
    __shared__ int sb[256];
    __shared__ int sd[256];
    __shared__ int sbx[256];
    int i = threadIdx.x;
    int bv = (i < nb) ? bsum[i] : 0;
    sb[i] = bv;
    __syncthreads();
    for (int off = 1; off < 256; off <<= 1) {
        int tv = (i >= off) ? sb[i - off] : 0;
        __syncthreads();
        sb[i] += tv;
        __syncthreads();
    }
    sbx[i] = sb[i] - bv;
    __syncthreads();
    int boff = sbx[blockIdx.x];

    int t = blockIdx.x * 256 + i;
    int v = (t < n) ? deg[t] + 1 : 0;
    sd[i] = v;
    __syncthreads();
    for (int off = 1; off < 256; off <<= 1) {
        int tv = (i >= off) ? sd[i - off] : 0;
        __syncthreads();
        sd[i] += tv;
        __syncthreads();
    }
    if (t < n) {
        int ex = boff + sd[i] - v;
        rowptr[t] = ex;
        cursor[t] = ex;
        if (t == n - 1) rowptr[n] = etot;
    }
}

// ---------------- fat kernel: weight transpose/cvt  ||  degree histogram ----------------
// blocks [0,832): wcvt of W0/W1/W2.  blocks [832, 832+nhb): hist, 4 strided edges/thread.
__global__ void k_wh(const float* __restrict__ W0, ushort* __restrict__ T0,
                     const float* __restrict__ W1, ushort* __restrict__ T1,
                     const float* __restrict__ W2, ushort* __restrict__ T2,
                     const int* __restrict__ dst, int* __restrict__ deg, int e, int nhb) {
    if (blockIdx.x >= 832) {
        int hb = blockIdx.x - 832;
        int base = hb * 256 + threadIdx.x;
        int stride = nhb * 256;
#pragma unroll
        for (int k = 0; k < 4; ++k) {
            int i = base + k * stride;
            if (i < e) atomicAdd(&deg[dst[i]], 1);
        }
        return;
    }
    int i = blockIdx.x * blockDim.x + threadIdx.x;
    if (i < 131072) {                    // 512x256
        int k = i >> 8, c = i & 255;
        T0[(size_t)c * 512 + k] = f2bf(W0[i]);
    } else if (i < 196608) {             // 256x256
        int j = i - 131072;
        int k = j >> 8, c = j & 255;
        T1[(size_t)c * 256 + k] = f2bf(W1[j]);
    } else if (i < 212992) {             // 256x64
        int j = i - 196608;
        int k = j >> 6, c = j & 63;
        T2[(size_t)c * 256 + k] = f2bf(W2[j]);
    }
}

// ---------------- fat kernel: scatter (CSR col build)  ||  GEMM layer 0 ----------------
// blocks [0, nsb): scatter, 4 strided edges/thread (atomic cursor + col write).
// blocks [nsb, nsb+1564): gemm L0 (K=512, BM=64, BN=128, Nc=256, A f32->bf16 via LDS,
// fp8 C store, fused alpha). Proven R12/R17 gemm body.
__global__ __launch_bounds__(256) void k_g0s(const float* __restrict__ Ap,
                                             const ushort* __restrict__ BT,
                                             unsigned char* __restrict__ Cp,
                                             const float* __restrict__ asv,
                                             const float* __restrict__ adv,
                                             float* __restrict__ asrc,
                                             float* __restrict__ adst, int M,
                                             const int* __restrict__ ei,
                                             int* __restrict__ cursor,
                                             int* __restrict__ colb,
                                             int E, int nsb) {
    constexpr int K = 512, BK = 32;
    constexpr int NK = K / BK;            // 16
    constexpr int AU = 256, BU = 512, TU = AU + BU;
    __shared__ __align__(16) ushort lds[2][TU * 8];

    if (blockIdx.x < nsb) {
        int base = blockIdx.x * 256 + threadIdx.x;
        int stride = nsb * 256;
        int etot = E + M;
#pragma unroll
        for (int k = 0; k < 4; ++k) {
            int i = base + k * stride;
            if (i < etot) {
                int s, d;
                if (i < E) { s = ei[i]; d = ei[E + i]; }
                else       { s = i - E; d = s; }
                int pos = atomicAdd(&cursor[d], 1);
                colb[pos] = s;
            }
        }
        return;
    }

    const int gb = blockIdx.x - nsb;
    const int t = threadIdx.x;
    const int wid = t >> 6, lane = t & 63;
    const int lr = lane & 15, lg = lane >> 4;
    const int wm = wid >> 1, wn = wid & 1;
    const int bm0 = (gb >> 1) * 64;
    const int bn0 = (gb & 1) * 128;

    int a_off[2], b_off[4];
#pragma unroll
    for (int mf = 0; mf < 2; ++mf) {
        int row = wm * 32 + mf * 16 + lr;
        a_off[mf] = row * 64 + ((lg ^ ((row >> 1) & 3)) << 4);
    }
#pragma unroll
    for (int nf = 0; nf < 4; ++nf) {
        int col = wn * 64 + nf * 16 + lr;
        b_off[nf] = AU * 16 + col * 64 + ((lg ^ ((col >> 1) & 3)) << 4);
    }

    f32x4 acc[2][4];
#pragma unroll
    for (int mf = 0; mf < 2; ++mf)
#pragma unroll
        for (int nf = 0; nf < 4; ++nf) acc[mf][nf] = f32x4{0.f, 0.f, 0.f, 0.f};

    f32x4 ra[2];

    auto stage_B = [&](int buf, int kk) {
#pragma unroll
        for (int i = 0; i < 2; ++i) {
            int u = t + i * 256;
            int col = u >> 2;
            int g = (u & 3) ^ ((col >> 1) & 3);
            const ushort* src = BT + (size_t)(bn0 + col) * K + kk + g * 8;
            gload16(src, &lds[buf][(AU + u) * 8]);
        }
    };
    auto load_A32 = [&](int kk) {
        int u = t;
        int row = u >> 2;
        int g = (u & 3) ^ ((row >> 1) & 3);
        int grow = bm0 + row;
        if (grow >= M) grow = M - 1;
        const float* src = Ap + (size_t)grow * K + kk + g * 8;
        ra[0] = *(const f32x4*)src;
        ra[1] = *(const f32x4*)(src + 4);
    };
    auto write_A32 = [&](int buf) {
        short8 v;
#pragma unroll
        for (int j = 0; j < 4; ++j) {
            v[j] = (short)f2bf(ra[0][j]);
            v[4 + j] = (short)f2bf(ra[1][j]);
        }
        *(short8*)&lds[buf][t * 8] = v;
    };
    auto compute = [&](int buf) {
        const char* base = (const char*)lds[buf];
        short8 af[2], bf_[4];
#pragma unroll
        for (int mf = 0; mf < 2; ++mf) af[mf] = *(const short8*)(base + a_off[mf]);
#pragma unroll
        for (int nf = 0; nf < 4; ++nf) bf_[nf] = *(const short8*)(base + b_off[nf]);
#pragma unroll
        for (int mf = 0; mf < 2; ++mf)
#pragma unroll
            for (int nf = 0; nf < 4; ++nf)
                acc[mf][nf] = __builtin_amdgcn_mfma_f32_16x16x32_bf16(af[mf], bf_[nf], acc[mf][nf], 0, 0, 0);
    };

    load_A32(0);
    write_A32(0);
    stage_B(0, 0);
    __syncthreads();

    int buf = 0;
    for (int ks = 0; ks < NK; ++ks) {
        const int kk = (ks + 1) * BK;
        if (ks + 1 < NK) {
            load_A32(kk);
            stage_B(buf ^ 1, kk);
        }
        compute(buf);
        if (ks + 1 < NK) write_A32(buf ^ 1);
        __syncthreads();
        buf ^= 1;
    }

    // epilogue: C store (fp8 e4m3)
#pragma unroll
    for (int mf = 0; mf < 2; ++mf) {
#pragma unroll
        for (int nf = 0; nf < 4; ++nf) {
            int col = bn0 + wn * 64 + nf * 16 + lr;
#pragma unroll
            for (int p = 0; p < 4; ++p) {
                int row = bm0 + wm * 32 + mf * 16 + lg * 4 + p;
                if (row < M)
                    Cp[(size_t)row * 256 + col] = f2fp8(acc[mf][nf][p]);
            }
        }
    }

    // fused alpha (wave spans 2 heads)
    {
        float cs[4], cd[4];
#pragma unroll
        for (int nf = 0; nf < 4; ++nf) {
            int col = bn0 + wn * 64 + nf * 16 + lr;
            cs[nf] = asv[col];
            cd[nf] = adv[col];
        }
        const int hb = (bn0 >> 5) + wn * 2;
#pragma unroll
        for (int mf = 0; mf < 2; ++mf) {
#pragma unroll
            for (int p = 0; p < 4; ++p) {
                float sA = acc[mf][0][p] * cs[0] + acc[mf][1][p] * cs[1];
                float sB = acc[mf][2][p] * cs[2] + acc[mf][3][p] * cs[3];
                float dA = acc[mf][0][p] * cd[0] + acc[mf][1][p] * cd[1];
                float dB = acc[mf][2][p] * cd[2] + acc[mf][3][p] * cd[3];
#pragma unroll
                for (int off = 1; off < 16; off <<= 1) {
                    sA += __shfl_xor(sA, off);
                    sB += __shfl_xor(sB, off);
                    dA += __shfl_xor(dA, off);
                    dB += __shfl_xor(dB, off);
                }
                int row = bm0 + wm * 32 + mf * 16 + lg * 4 + p;
                if (lr == 0 && row < M) {
                    asrc[row * 8 + hb] = sA;
                    asrc[row * 8 + hb + 1] = sB;
                    adst[row * 8 + hb] = dA;
                    adst[row * 8 + hb + 1] = dB;
                }
            }
        }
    }
}

// ---------------- GEMM layer 1 (bf16 A, K=256): proven R17 template path ----------------
template <int K, int BN>
__global__ __launch_bounds__(256) void k_gemm(const ushort* __restrict__ Ap,
                                              const ushort* __restrict__ BT,
                                              unsigned char* __restrict__ Cp,
                                              const float* __restrict__ asv,
                                              const float* __restrict__ adv,
                                              float* __restrict__ asrc,
                                              float* __restrict__ adst, int M) {
    constexpr int BM = 64, BK = 32;
    constexpr int NK = K / BK;
    constexpr int NF = BN / 32;
    constexpr int AU = BM * BK / 8;
    constexpr int BU = BN * BK / 8;
    constexpr int TU = AU + BU;
    __shared__ __align__(16) ushort lds[2][TU * 8];

    const int t = threadIdx.x;
    const int wid = t >> 6, lane = t & 63;
    const int lr = lane & 15, lg = lane >> 4;
    const int wm = wid >> 1, wn = wid & 1;
    const int bm0 = blockIdx.x * BM;
    const int bn0 = blockIdx.y * BN;
    const int Nc = BN * gridDim.y;

    int a_off[2], b_off[NF];
#pragma unroll
    for (int mf = 0; mf < 2; ++mf) {
        int row = wm * 32 + mf * 16 + lr;
        a_off[mf] = row * 64 + ((lg ^ ((row >> 1) & 3)) << 4);
    }
#pragma unroll
    for (int nf = 0; nf < NF; ++nf) {
        int col = wn * (BN / 2) + nf * 16 + lr;
        b_off[nf] = AU * 16 + col * 64 + ((lg ^ ((col >> 1) & 3)) << 4);
    }

    f32x4 acc[2][NF];
#pragma unroll
    for (int mf = 0; mf < 2; ++mf)
#pragma unroll
        for (int nf = 0; nf < NF; ++nf) acc[mf][nf] = f32x4{0.f, 0.f, 0.f, 0.f};

    auto stage_B = [&](int buf, int kk) {
#pragma unroll
        for (int i = 0; i < 2; ++i) {
            int u = t + i * 256;
            int col = u >> 2;
            int g = (u & 3) ^ ((col >> 1) & 3);
            const ushort* src = BT + (size_t)(bn0 + col) * K + kk + g * 8;
            gload16(src, &lds[buf][(AU + u) * 8]);
        }
    };
    auto stage_A16 = [&](int buf, int kk) {
        int u = t;
        int row = u >> 2;
        int g = (u & 3) ^ ((row >> 1) & 3);
        int grow = bm0 + row;
        if (grow >= M) grow = M - 1;
        const ushort* src = Ap + (size_t)grow * K + kk + g * 8;
        gload16(src, &lds[buf][u * 8]);
    };
    auto compute = [&](int buf) {
        const char* base = (const char*)lds[buf];
        short8 af[2], bf_[NF];
#pragma unroll
        for (int mf = 0; mf < 2; ++mf) af[mf] = *(const short8*)(base + a_off[mf]);
#pragma unroll
        for (int nf = 0; nf < NF; ++nf) bf_[nf] = *(const short8*)(base + b_off[nf]);
#pragma unroll
        for (int mf = 0; mf < 2; ++mf)
#pragma unroll
            for (int nf = 0; nf < NF; ++nf)
                acc[mf][nf] = __builtin_amdgcn_mfma_f32_16x16x32_bf16(af[mf], bf_[nf], acc[mf][nf], 0, 0, 0);
    };

    stage_A16(0, 0);
    stage_B(0, 0);
    __syncthreads();

    int buf = 0;
    for (int ks = 0; ks < NK; ++ks) {
        const int kk = (ks + 1) * BK;
        if (ks + 1 < NK) {
            stage_A16(buf ^ 1, kk);
            stage_B(buf ^ 1, kk);
        }
        compute(buf);
        __syncthreads();
        buf ^= 1;
    }

#pragma unroll
    for (int mf = 0; mf < 2; ++mf) {
#pragma unroll
        for (int nf = 0; nf < NF; ++nf) {
            int col = bn0 + wn * (BN / 2) + nf * 16 + lr;
#pragma unroll
            for (int p = 0; p < 4; ++p) {
                int row = bm0 + wm * 32 + mf * 16 + lg * 4 + p;
                if (row < M)
                    Cp[(size_t)row * Nc + col] = f2fp8(acc[mf][nf][p]);
            }
        }
    }

    if constexpr (NF == 4) {
        float cs[4], cd[4];
#pragma unroll
        for (int nf = 0; nf < 4; ++nf) {
            int col = bn0 + wn * 64 + nf * 16 + lr;
            cs[nf] = asv[col];
            cd[nf] = adv[col];
        }
        const int hb = (bn0 >> 5) + wn * 2;
#pragma unroll
        for (int mf = 0; mf < 2; ++mf) {
#pragma unroll
            for (int p = 0; p < 4; ++p) {
                float sA = acc[mf][0][p] * cs[0] + acc[mf][1][p] * cs[1];
                float sB = acc[mf][2][p] * cs[2] + acc[mf][3][p] * cs[3];
                float dA = acc[mf][0][p] * cd[0] + acc[mf][1][p] * cd[1];
                float dB = acc[mf][2][p] * cd[2] + acc[mf][3][p] * cd[3];
#pragma unroll
                for (int off = 1; off < 16; off <<= 1) {
                    sA += __shfl_xor(sA, off);
                    sB += __shfl_xor(sB, off);
                    dA += __shfl_xor(dA, off);
                    dB += __shfl_xor(dB, off);
                }
                int row = bm0 + wm * 32 + mf * 16 + lg * 4 + p;
                if (lr == 0 && row < M) {
                    asrc[row * 8 + hb] = sA;
                    asrc[row * 8 + hb + 1] = sB;
                    adst[row * 8 + hb] = dA;
                    adst[row * 8 + hb + 1] = dB;
                }
            }
        }
    }
}

// ---------------- GEMM layer 2 (K=256, Nc=64), BM=64, bf16 store + fused alpha2 ----------------
__global__ __launch_bounds__(256) void k_gemm2(const ushort* __restrict__ Ap,
                                               const ushort* __restrict__ BT,
                                               ushort* __restrict__ Cp,
                                               const float* __restrict__ asv,
                                               const float* __restrict__ adv,
                                               float* __restrict__ asrc,
                                               float* __restrict__ adst, int M) {
    constexpr int K = 256, BM = 64, BK = 32;
    constexpr int NK = K / BK;
    constexpr int BU = 64 * BK / 8;   // 256
    constexpr int AU = BM * BK / 8;   // 256
    constexpr int TU = AU + BU;
    __shared__ __align__(16) ushort lds[2][TU * 8];

    const int t = threadIdx.x;
    const int wid = t >> 6, lane = t & 63;
    const int lr = lane & 15, lg = lane >> 4;
    const int bm0 = blockIdx.x * BM;

    int a_off0, b_off[4];
    {
        int row = wid * 16 + lr;
        a_off0 = row * 64 + ((lg ^ ((row >> 1) & 3)) << 4);
    }
#pragma unroll
    for (int nf = 0; nf < 4; ++nf) {
        int col = nf * 16 + lr;
        b_off[nf] = AU * 16 + col * 64 + ((lg ^ ((col >> 1) & 3)) << 4);
    }

    f32x4 acc[4];
#pragma unroll
    for (int nf = 0; nf < 4; ++nf) acc[nf] = f32x4{0.f, 0.f, 0.f, 0.f};

    auto stage_B = [&](int buf, int kk) {
        int u = t;
        int col = u >> 2;
        int g = (u & 3) ^ ((col >> 1) & 3);
        const ushort* src = BT + (size_t)col * K + kk + g * 8;
        gload16(src, &lds[buf][(AU + u) * 8]);
    };
    auto stage_A = [&](int buf, int kk) {
        int u = t;
        int row = u >> 2;
        int g = (u & 3) ^ ((row >> 1) & 3);
        int grow = bm0 + row;
        if (grow >= M) grow = M - 1;
        const ushort* src = Ap + (size_t)grow * K + kk + g * 8;
        gload16(src, &lds[buf][u * 8]);
    };
    auto compute = [&](int buf) {
        const char* base = (const char*)lds[buf];
        short8 af = *(const short8*)(base + a_off0);
        short8 bf_[4];
#pragma unroll
        for (int nf = 0; nf < 4; ++nf) bf_[nf] = *(const short8*)(base + b_off[nf]);
#pragma unroll
        for (int nf = 0; nf < 4; ++nf)
            acc[nf] = __builtin_amdgcn_mfma_f32_16x16x32_bf16(af, bf_[nf], acc[nf], 0, 0, 0);
    };

    stage_A(0, 0);
    stage_B(0, 0);
    __syncthreads();
    int buf = 0;
    for (int ks = 0; ks < NK; ++ks) {
        if (ks + 1 < NK) {
            stage_A(buf ^ 1, (ks + 1) * BK);
            stage_B(buf ^ 1, (ks + 1) * BK);
        }
        compute(buf);
        __syncthreads();
        buf ^= 1;
    }

    float cs[4], cd[4];
#pragma unroll
    for (int nf = 0; nf < 4; ++nf) {
        cs[nf] = asv[nf * 16 + lr];
        cd[nf] = adv[nf * 16 + lr];
    }
#pragma unroll
    for (int p = 0; p < 4; ++p) {
        int row = bm0 + wid * 16 + lg * 4 + p;
#pragma unroll
        for (int nf = 0; nf < 4; ++nf) {
            if (row < M)
                Cp[(size_t)row * 64 + nf * 16 + lr] = f2bf(acc[nf][p]);
        }
        float sA = acc[0][p] * cs[0] + acc[1][p] * cs[1] +
                   acc[2][p] * cs[2] + acc[3][p] * cs[3];
        float dA = acc[0][p] * cd[0] + acc[1][p] * cd[1] +
                   acc[2][p] * cd[2] + acc[3][p] * cd[3];
#pragma unroll
        for (int off = 1; off < 16; off <<= 1) {
            sA += __shfl_xor(sA, off);
            dA += __shfl_xor(dA, off);
        }
        if (lr == 0 && row < M) {
            asrc[row] = sA;
            adst[row] = dA;
        }
    }
}

// ---------------- fused softmax+aggregation, layers 0/1: h gathered as fp8 e4m3 ----------------
#define MAXW 96
__global__ __launch_bounds__(128) void k_agg(const unsigned char* __restrict__ h8,
                                             const float* __restrict__ asrc,
                                             const float* __restrict__ adst,
                                             const int* __restrict__ rowptr,
                                             const int* __restrict__ col,
                                             const float* __restrict__ bias,
                                             ushort* __restrict__ anext, int n) {
    __shared__ float wl[2][MAXW * 8];
    int wid = threadIdx.x >> 6;
    int lane = threadIdx.x & 63;
    int node = blockIdx.x * 2 + wid;
    if (node >= n) return;
    int beg = rowptr[node], end = rowptr[node + 1];
    int deg = end - beg;
    int hd = lane >> 3;
    int eo = lane & 7;
    float ad = adst[node * 8 + hd];
    float* wp = wl[wid];

    float sacc = 0.f;
    for (int jb = eo; jb < deg; jb += 8) {
        int s = col[beg + jb];
        float w = __expf(lrelu(asrc[s * 8 + hd] + ad));
        if (jb < MAXW) wp[jb * 8 + hd] = w;
        sacc += w;
    }
    sacc += __shfl_xor(sacc, 1);
    sacc += __shfl_xor(sacc, 2);
    sacc += __shfl_xor(sacc, 4);
    float inv = 1.f / (sacc + 1e-16f);

    int nl = (deg < MAXW) ? deg : MAXW;
    float a0 = 0.f, a1 = 0.f, a2 = 0.f, a3 = 0.f;
    int jb = 0;
    for (; jb + 8 <= nl; jb += 8) {
        int sv[8];
#pragma unroll
        for (int i = 0; i < 8; ++i) sv[i] = col[beg + jb + i];
        unsigned gv[8];
#pragma unroll
        for (int i = 0; i < 8; ++i) gv[i] = *(const unsigned*)(h8 + (size_t)sv[i] * 256 + lane * 4);
        float wv[8];
#pragma unroll
        for (int i = 0; i < 8; ++i) wv[i] = wp[(jb + i) * 8 + hd];
#pragma unroll
        for (int i = 0; i < 8; ++i) {
            a0 += wv[i] * __builtin_amdgcn_cvt_f32_fp8(gv[i], 0);
            a1 += wv[i] * __builtin_amdgcn_cvt_f32_fp8(gv[i], 1);
            a2 += wv[i] * __builtin_amdgcn_cvt_f32_fp8(gv[i], 2);
            a3 += wv[i] * __builtin_amdgcn_cvt_f32_fp8(gv[i], 3);
        }
    }
    for (; jb < nl; ++jb) {
        int s = col[beg + jb];
        unsigned g = *(const unsigned*)(h8 + (size_t)s * 256 + lane * 4);
        float w = wp[jb * 8 + hd];
        a0 += w * __builtin_amdgcn_cvt_f32_fp8(g, 0);
        a1 += w * __builtin_amdgcn_cvt_f32_fp8(g, 1);
        a2 += w * __builtin_amdgcn_cvt_f32_fp8(g, 2);
        a3 += w * __builtin_amdgcn_cvt_f32_fp8(g, 3);
    }
    for (; jb < deg; ++jb) {
        int s = col[beg + jb];
        unsigned g = *(const unsigned*)(h8 + (size_t)s * 256 + lane * 4);
        float w = __expf(lrelu(asrc[s * 8 + hd] + ad));
        a0 += w * __builtin_amdgcn_cvt_f32_fp8(g, 0);
        a1 += w * __builtin_amdgcn_cvt_f32_fp8(g, 1);
        a2 += w * __builtin_amdgcn_cvt_f32_fp8(g, 2);
        a3 += w * __builtin_amdgcn_cvt_f32_fp8(g, 3);
    }
    f32x4 bv = *(const f32x4*)(bias + lane * 4);
    float v0 = a0 * inv + bv[0];
    float v1 = a1 * inv + bv[1];
    float v2 = a2 * inv + bv[2];
    float v3 = a3 * inv + bv[3];
    v0 = (v0 > 0.f) ? v0 : expm1f(v0);
    v1 = (v1 > 0.f) ? v1 : expm1f(v1);
    v2 = (v2 > 0.f) ? v2 : expm1f(v2);
    v3 = (v3 > 0.f) ? v3 : expm1f(v3);
    us4 o;
    o[0] = f2bf(v0); o[1] = f2bf(v1); o[2] = f2bf(v2); o[3] = f2bf(v3);
    *(us4*)(anext + (size_t)node * 256 + lane * 4) = o;
}

// ---------------- fused layer 2 + bias + log_softmax ----------------
__global__ __launch_bounds__(128) void k_agg2(const ushort* __restrict__ h2,
                                              const float* __restrict__ asrc,
                                              const float* __restrict__ adst,
                                              const int* __restrict__ rowptr,
                                              const int* __restrict__ col,
                                              const float* __restrict__ bias,
                                              float* __restrict__ out, int n) {
    int wid = threadIdx.x >> 6;
    int lane = threadIdx.x & 63;
    int node = blockIdx.x * 2 + wid;
    if (node >= n) return;
    int beg = rowptr[node], end = rowptr[node + 1];
    int deg = end - beg;
    float ad = adst[node];
    int g = lane >> 3;
    int ch = (lane & 7) * 8;

    f32x2 acc2[4];
#pragma unroll
    for (int i = 0; i < 4; ++i) acc2[i] = f32x2{0.f, 0.f};
    float ssum = 0.f;
    for (int p = 0; p < deg; p += 8) {
        int jb = p + g;
        float w = 0.f;
        uint4 gv = {0u, 0u, 0u, 0u};
        if (jb < deg) {
            int s = col[beg + jb];
            gv = *(const uint4*)(h2 + (size_t)s * 64 + ch);
            w = __expf(lrelu(asrc[s] + ad));
        }
        ssum += w;
        f32x2 w2 = {w, w};
        f32x2 p0 = {__uint_as_float(gv.x << 16), __uint_as_float(gv.x & 0xFFFF0000u)};
        f32x2 p1 = {__uint_as_float(gv.y << 16), __uint_as_float(gv.y & 0xFFFF0000u)};
        f32x2 p2 = {__uint_as_float(gv.z << 16), __uint_as_float(gv.z & 0xFFFF0000u)};
        f32x2 p3 = {__uint_as_float(gv.w << 16), __uint_as_float(gv.w & 0xFFFF0000u)};
        acc2[0] += w2 * p0;
        acc2[1] += w2 * p1;
        acc2[2] += w2 * p2;
        acc2[3] += w2 * p3;
    }
    float v[8];
#pragma unroll
    for (int i = 0; i < 4; ++i) { v[2 * i] = acc2[i].x; v[2 * i + 1] = acc2[i].y; }
#pragma unroll
    for (int off = 8; off < 64; off <<= 1) {
        ssum += __shfl_xor(ssum, off);
#pragma unroll
        for (int i = 0; i < 8; ++i) v[i] += __shfl_xor(v[i], off);
    }
    float inv = 1.f / (ssum + 1e-16f);
#pragma unroll
    for (int i = 0; i < 8; ++i) v[i] = v[i] * inv + bias[ch + i];
    float mx = v[0];
#pragma unroll
    for (int i = 1; i < 8; ++i) mx = fmaxf(mx, v[i]);
    mx = fmaxf(mx, __shfl_xor(mx, 1));
    mx = fmaxf(mx, __shfl_xor(mx, 2));
    mx = fmaxf(mx, __shfl_xor(mx, 4));
    float se = 0.f;
#pragma unroll
    for (int i = 0; i < 8; ++i) se += __expf(v[i] - mx);
    se += __shfl_xor(se, 1);
    se += __shfl_xor(se, 2);
    se += __shfl_xor(se, 4);
    float ls = mx + logf(se);
    if (g == 0) {
        f32x4 o0, o1;
#pragma unroll
        for (int i = 0; i < 4; ++i) { o0[i] = v[i] - ls; o1[i] = v[4 + i] - ls; }
        *(f32x4*)(out + (size_t)node * 64 + ch) = o0;
        *(f32x4*)(out + (size_t)node * 64 + ch + 4) = o1;
    }
}

extern "C" void kernel_launch(void* const* d_in, const int* in_sizes, int n_in,
                              void* d_out, int out_size, void* d_ws, size_t ws_size,
                              hipStream_t stream) {
    const float* x   = (const float*)d_in[0];
    const int*   ei  = (const int*)d_in[1];
    const float* W0  = (const float*)d_in[2];
    const float* as0 = (const float*)d_in[3];
    const float* ad0 = (const float*)d_in[4];
    const float* b0  = (const float*)d_in[5];
    const float* W1  = (const float*)d_in[6];
    const float* as1 = (const float*)d_in[7];
    const float* ad1 = (const float*)d_in[8];
    const float* b1  = (const float*)d_in[9];
    const float* W2  = (const float*)d_in[10];
    const float* as2 = (const float*)d_in[11];
    const float* ad2 = (const float*)d_in[12];
    const float* b2  = (const float*)d_in[13];
    float* out = (float*)d_out;

    const int N = in_sizes[0] / 512;   // 50000
    const int E = in_sizes[1] / 2;     // 800000
    const int ETOT = E + N;

    char* ws = (char*)d_ws;
    size_t off = 0;
    auto alloc = [&](size_t bytes) -> void* {
        off = (off + 255) & ~(size_t)255;
        void* p = ws + off;
        off += bytes;
        return p;
    };
    int* rowptr = (int*)alloc((size_t)(N + 1) * 4);
    int* cursor = (int*)alloc((size_t)N * 4);
    int* deg    = (int*)alloc((size_t)N * 4);
    int* bsum   = (int*)alloc(1024);
    int* colb   = (int*)alloc((size_t)ETOT * 4);
    ushort* WT0 = (ushort*)alloc((size_t)256 * 512 * 2);
    ushort* WT1 = (ushort*)alloc((size_t)256 * 256 * 2);
    ushort* WT2 = (ushort*)alloc((size_t)64 * 256 * 2);
    unsigned char* h8 = (unsigned char*)alloc((size_t)N * 256);  // fp8 h
    ushort* abf = (ushort*)alloc((size_t)N * 256 * 2);
    float* asrc = (float*)alloc((size_t)N * 8 * 4);
    float* adst = (float*)alloc((size_t)N * 8 * 4);
    // aliases (lifetimes disjoint)
    ushort* h2   = (ushort*)h8;
    float* asrc2 = asrc;
    float* adst2 = adst;

    const int nblk = (N + 255) / 256;        // 196
    const int nhb  = (E + 1023) / 1024;      // 782 hist blocks
    const int nsb  = (ETOT + 1023) / 1024;   // 831 scatter blocks

    // deg zeroing, then fat: weight cvt || histogram
    hipMemsetAsync(deg, 0, (size_t)N * 4, stream);
    k_wh<<<832 + nhb, 256, 0, stream>>>(W0, WT0, W1, WT1, W2, WT2, ei + E, deg, E, nhb);

    // scans
    k_scanA<<<nblk, 256, 0, stream>>>(deg, bsum, N);
    k_scanC<<<nblk, 256, 0, stream>>>(deg, bsum, rowptr, cursor, N, ETOT, nblk);

    const int gblk = (N + 63) / 64;          // 782
    const int ablk = (N + 1) / 2;            // 25000

    // fat: scatter || gemm layer 0
    k_g0s<<<nsb + 2 * gblk, 256, 0, stream>>>(x, WT0, h8, as0, ad0, asrc, adst, N,
                                              ei, cursor, colb, E, nsb);
    k_agg<<<ablk, 128, 0, stream>>>(h8, asrc, adst, rowptr, colb, b0, abf, N);

    // layer 1
    k_gemm<256, 128><<<dim3(gblk, 2), 256, 0, stream>>>(abf, WT1, h8, as1, ad1, asrc, adst, N);
    k_agg<<<ablk, 128, 0, stream>>>(h8, asrc, adst, rowptr, colb, b1, abf, N);

    // layer 2 (gemm + fused alpha2)
    k_gemm2<<<gblk, 256, 0, stream>>>(abf, WT2, h2, as2, ad2, asrc2, adst2, N);
    k_agg2<<<ablk, 128, 0, stream>>>(h2, asrc2, adst2, rowptr, colb, b2, out, N);
}

// Round 19
// 297.085 us; speedup vs baseline: 1.1053x; 1.1053x over previous
//
#include <hip/hip_runtime.h>
#include <hip/hip_bf16.h>

typedef __attribute__((ext_vector_type(8))) short short8;
typedef __attribute__((ext_vector_type(4))) float f32x4;
typedef __attribute__((ext_vector_type(2))) float f32x2;
typedef __attribute__((ext_vector_type(4))) unsigned short us4;

__device__ __forceinline__ ushort f2bf(float f) {
    unsigned u = __float_as_uint(f);
    u += 0x7FFFu + ((u >> 16) & 1u);
    return (ushort)(u >> 16);
}
__device__ __forceinline__ float bf2f(ushort h) {
    return __uint_as_float(((unsigned)h) << 16);
}
__device__ __forceinline__ float lrelu(float e) { return (e >= 0.f) ? e : 0.2f * e; }
__device__ __forceinline__ unsigned char f2fp8(float v) {
    return (unsigned char)(__builtin_amdgcn_cvt_pk_fp8_f32(v, v, 0, false) & 0xFF);
}
__device__ __forceinline__ void gload16(const void* g, void* l) {
    __builtin_amdgcn_global_load_lds(
        (const __attribute__((address_space(1))) unsigned int*)g,
        (__attribute__((address_space(3))) unsigned int*)l, 16, 0, 0);
}

// ---------------- CSR scans ----------------
__global__ void k_scanA(const int* __restrict__ deg, int* __restrict__ bsum, int n) {
    __shared__ int sd[256];
    int t = blockIdx.x * 256 + threadIdx.x;
    sd[threadIdx.x] = (t < n) ? deg[t] + 1 : 0;
    __syncthreads();
    for (int off = 128; off > 0; off >>= 1) {
        if (threadIdx.x < off) sd[threadIdx.x] += sd[threadIdx.x + off];
        __syncthreads();
    }
    if (threadIdx.x == 0) bsum[blockIdx.x] = sd[0];
}
__global__ void k_scanC(const int* __restrict__ deg, const int* __restrict__ bsum,
                        int* __restrict__ rowptr, int* __restrict__ cursor,
                        int n, int etot, int nb) {
    __shared__ int sb[256];
    __shared__ int sd[256];
    __shared__ int sbx[256];
    int i = threadIdx.x;
    int bv = (i < nb) ? bsum[i] : 0;
    sb[i] = bv;
    __syncthreads();
    for (int off = 1; off < 256; off <<= 1) {
        int tv = (i >= off) ? sb[i - off] : 0;
        __syncthreads();
        sb[i] += tv;
        __syncthreads();
    }
    sbx[i] = sb[i] - bv;
    __syncthreads();
    int boff = sbx[blockIdx.x];

    int t = blockIdx.x * 256 + i;
    int v = (t < n) ? deg[t] + 1 : 0;
    sd[i] = v;
    __syncthreads();
    for (int off = 1; off < 256; off <<= 1) {
        int tv = (i >= off) ? sd[i - off] : 0;
        __syncthreads();
        sd[i] += tv;
        __syncthreads();
    }
    if (t < n) {
        int ex = boff + sd[i] - v;
        rowptr[t] = ex;
        cursor[t] = ex;
        if (t == n - 1) rowptr[n] = etot;
    }
}

// ---------------- fat kernel: weight transpose/cvt  ||  degree histogram ----------------
__global__ void k_wh(const float* __restrict__ W0, ushort* __restrict__ T0,
                     const float* __restrict__ W1, ushort* __restrict__ T1,
                     const float* __restrict__ W2, ushort* __restrict__ T2,
                     const int* __restrict__ dst, int* __restrict__ deg, int e, int nhb) {
    if (blockIdx.x >= 832) {
        int hb = blockIdx.x - 832;
        int base = hb * 256 + threadIdx.x;
        int stride = nhb * 256;
#pragma unroll
        for (int k = 0; k < 4; ++k) {
            int i = base + k * stride;
            if (i < e) atomicAdd(&deg[dst[i]], 1);
        }
        return;
    }
    int i = blockIdx.x * blockDim.x + threadIdx.x;
    if (i < 131072) {                    // 512x256
        int k = i >> 8, c = i & 255;
        T0[(size_t)c * 512 + k] = f2bf(W0[i]);
    } else if (i < 196608) {             // 256x256
        int j = i - 131072;
        int k = j >> 8, c = j & 255;
        T1[(size_t)c * 256 + k] = f2bf(W1[j]);
    } else if (i < 212992) {             // 256x64
        int j = i - 196608;
        int k = j >> 6, c = j & 63;
        T2[(size_t)c * 256 + k] = f2bf(W2[j]);
    }
}

// ---------------- fat kernel: scatter || GEMM layer 0, INTERLEAVED block roles ----------------
// bid&3==3 -> scatter block sid=bid>>2 (4 strided edges/thread); else gemm gid=bid-(bid>>2).
// gemm: K=512, BM=64, BN=128, Nc=256, f32 A via LDS reg-cvt, fp8 C, fused alpha (proven body).
__global__ __launch_bounds__(256) void k_g0s(const float* __restrict__ Ap,
                                             const ushort* __restrict__ BT,
                                             unsigned char* __restrict__ Cp,
                                             const float* __restrict__ asv,
                                             const float* __restrict__ adv,
                                             float* __restrict__ asrc,
                                             float* __restrict__ adst, int M,
                                             const int* __restrict__ ei,
                                             int* __restrict__ cursor,
                                             int* __restrict__ colb,
                                             int E, int nsb, int ngb) {
    constexpr int K = 512, BK = 32;
    constexpr int NK = K / BK;            // 16
    constexpr int AU = 256, BU = 512, TU = AU + BU;
    __shared__ __align__(16) ushort lds[2][TU * 8];

    const int bid = blockIdx.x;
    if ((bid & 3) == 3) {
        int sid = bid >> 2;
        if (sid < nsb) {
            int base = sid * 256 + threadIdx.x;
            int stride = nsb * 256;
            int etot = E + M;
#pragma unroll
            for (int k = 0; k < 4; ++k) {
                int i = base + k * stride;
                if (i < etot) {
                    int s, d;
                    if (i < E) { s = ei[i]; d = ei[E + i]; }
                    else       { s = i - E; d = s; }
                    int pos = atomicAdd(&cursor[d], 1);
                    colb[pos] = s;
                }
            }
        }
        return;
    }
    const int gb = bid - (bid >> 2);
    if (gb >= ngb) return;

    const int t = threadIdx.x;
    const int wid = t >> 6, lane = t & 63;
    const int lr = lane & 15, lg = lane >> 4;
    const int wm = wid >> 1, wn = wid & 1;
    const int bm0 = (gb >> 1) * 64;
    const int bn0 = (gb & 1) * 128;

    int a_off[2], b_off[4];
#pragma unroll
    for (int mf = 0; mf < 2; ++mf) {
        int row = wm * 32 + mf * 16 + lr;
        a_off[mf] = row * 64 + ((lg ^ ((row >> 1) & 3)) << 4);
    }
#pragma unroll
    for (int nf = 0; nf < 4; ++nf) {
        int col = wn * 64 + nf * 16 + lr;
        b_off[nf] = AU * 16 + col * 64 + ((lg ^ ((col >> 1) & 3)) << 4);
    }

    f32x4 acc[2][4];
#pragma unroll
    for (int mf = 0; mf < 2; ++mf)
#pragma unroll
        for (int nf = 0; nf < 4; ++nf) acc[mf][nf] = f32x4{0.f, 0.f, 0.f, 0.f};

    f32x4 ra[2];

    auto stage_B = [&](int buf, int kk) {
#pragma unroll
        for (int i = 0; i < 2; ++i) {
            int u = t + i * 256;
            int col = u >> 2;
            int g = (u & 3) ^ ((col >> 1) & 3);
            const ushort* src = BT + (size_t)(bn0 + col) * K + kk + g * 8;
            gload16(src, &lds[buf][(AU + u) * 8]);
        }
    };
    auto load_A32 = [&](int kk) {
        int u = t;
        int row = u >> 2;
        int g = (u & 3) ^ ((row >> 1) & 3);
        int grow = bm0 + row;
        if (grow >= M) grow = M - 1;
        const float* src = Ap + (size_t)grow * K + kk + g * 8;
        ra[0] = *(const f32x4*)src;
        ra[1] = *(const f32x4*)(src + 4);
    };
    auto write_A32 = [&](int buf) {
        short8 v;
#pragma unroll
        for (int j = 0; j < 4; ++j) {
            v[j] = (short)f2bf(ra[0][j]);
            v[4 + j] = (short)f2bf(ra[1][j]);
        }
        *(short8*)&lds[buf][t * 8] = v;
    };
    auto compute = [&](int buf) {
        const char* base = (const char*)lds[buf];
        short8 af[2], bf_[4];
#pragma unroll
        for (int mf = 0; mf < 2; ++mf) af[mf] = *(const short8*)(base + a_off[mf]);
#pragma unroll
        for (int nf = 0; nf < 4; ++nf) bf_[nf] = *(const short8*)(base + b_off[nf]);
#pragma unroll
        for (int mf = 0; mf < 2; ++mf)
#pragma unroll
            for (int nf = 0; nf < 4; ++nf)
                acc[mf][nf] = __builtin_amdgcn_mfma_f32_16x16x32_bf16(af[mf], bf_[nf], acc[mf][nf], 0, 0, 0);
    };

    load_A32(0);
    write_A32(0);
    stage_B(0, 0);
    __syncthreads();

    int buf = 0;
    for (int ks = 0; ks < NK; ++ks) {
        const int kk = (ks + 1) * BK;
        if (ks + 1 < NK) {
            load_A32(kk);
            stage_B(buf ^ 1, kk);
        }
        compute(buf);
        if (ks + 1 < NK) write_A32(buf ^ 1);
        __syncthreads();
        buf ^= 1;
    }

#pragma unroll
    for (int mf = 0; mf < 2; ++mf) {
#pragma unroll
        for (int nf = 0; nf < 4; ++nf) {
            int col = bn0 + wn * 64 + nf * 16 + lr;
#pragma unroll
            for (int p = 0; p < 4; ++p) {
                int row = bm0 + wm * 32 + mf * 16 + lg * 4 + p;
                if (row < M)
                    Cp[(size_t)row * 256 + col] = f2fp8(acc[mf][nf][p]);
            }
        }
    }

    {
        float cs[4], cd[4];
#pragma unroll
        for (int nf = 0; nf < 4; ++nf) {
            int col = bn0 + wn * 64 + nf * 16 + lr;
            cs[nf] = asv[col];
            cd[nf] = adv[col];
        }
        const int hb = (bn0 >> 5) + wn * 2;
#pragma unroll
        for (int mf = 0; mf < 2; ++mf) {
#pragma unroll
            for (int p = 0; p < 4; ++p) {
                float sA = acc[mf][0][p] * cs[0] + acc[mf][1][p] * cs[1];
                float sB = acc[mf][2][p] * cs[2] + acc[mf][3][p] * cs[3];
                float dA = acc[mf][0][p] * cd[0] + acc[mf][1][p] * cd[1];
                float dB = acc[mf][2][p] * cd[2] + acc[mf][3][p] * cd[3];
#pragma unroll
                for (int off = 1; off < 16; off <<= 1) {
                    sA += __shfl_xor(sA, off);
                    sB += __shfl_xor(sB, off);
                    dA += __shfl_xor(dA, off);
                    dB += __shfl_xor(dB, off);
                }
                int row = bm0 + wm * 32 + mf * 16 + lg * 4 + p;
                if (lr == 0 && row < M) {
                    asrc[row * 8 + hb] = sA;
                    asrc[row * 8 + hb + 1] = sB;
                    adst[row * 8 + hb] = dA;
                    adst[row * 8 + hb + 1] = dB;
                }
            }
        }
    }
}

// ---------------- GEMM layer 1 (bf16 A, K=256) ----------------
template <int K, int BN>
__global__ __launch_bounds__(256) void k_gemm(const ushort* __restrict__ Ap,
                                              const ushort* __restrict__ BT,
                                              unsigned char* __restrict__ Cp,
                                              const float* __restrict__ asv,
                                              const float* __restrict__ adv,
                                              float* __restrict__ asrc,
                                              float* __restrict__ adst, int M) {
    constexpr int BM = 64, BK = 32;
    constexpr int NK = K / BK;
    constexpr int NF = BN / 32;
    constexpr int AU = BM * BK / 8;
    constexpr int BU = BN * BK / 8;
    constexpr int TU = AU + BU;
    __shared__ __align__(16) ushort lds[2][TU * 8];

    const int t = threadIdx.x;
    const int wid = t >> 6, lane = t & 63;
    const int lr = lane & 15, lg = lane >> 4;
    const int wm = wid >> 1, wn = wid & 1;
    const int bm0 = blockIdx.x * BM;
    const int bn0 = blockIdx.y * BN;
    const int Nc = BN * gridDim.y;

    int a_off[2], b_off[NF];
#pragma unroll
    for (int mf = 0; mf < 2; ++mf) {
        int row = wm * 32 + mf * 16 + lr;
        a_off[mf] = row * 64 + ((lg ^ ((row >> 1) & 3)) << 4);
    }
#pragma unroll
    for (int nf = 0; nf < NF; ++nf) {
        int col = wn * (BN / 2) + nf * 16 + lr;
        b_off[nf] = AU * 16 + col * 64 + ((lg ^ ((col >> 1) & 3)) << 4);
    }

    f32x4 acc[2][NF];
#pragma unroll
    for (int mf = 0; mf < 2; ++mf)
#pragma unroll
        for (int nf = 0; nf < NF; ++nf) acc[mf][nf] = f32x4{0.f, 0.f, 0.f, 0.f};

    auto stage_B = [&](int buf, int kk) {
#pragma unroll
        for (int i = 0; i < 2; ++i) {
            int u = t + i * 256;
            int col = u >> 2;
            int g = (u & 3) ^ ((col >> 1) & 3);
            const ushort* src = BT + (size_t)(bn0 + col) * K + kk + g * 8;
            gload16(src, &lds[buf][(AU + u) * 8]);
        }
    };
    auto stage_A16 = [&](int buf, int kk) {
        int u = t;
        int row = u >> 2;
        int g = (u & 3) ^ ((row >> 1) & 3);
        int grow = bm0 + row;
        if (grow >= M) grow = M - 1;
        const ushort* src = Ap + (size_t)grow * K + kk + g * 8;
        gload16(src, &lds[buf][u * 8]);
    };
    auto compute = [&](int buf) {
        const char* base = (const char*)lds[buf];
        short8 af[2], bf_[NF];
#pragma unroll
        for (int mf = 0; mf < 2; ++mf) af[mf] = *(const short8*)(base + a_off[mf]);
#pragma unroll
        for (int nf = 0; nf < NF; ++nf) bf_[nf] = *(const short8*)(base + b_off[nf]);
#pragma unroll
        for (int mf = 0; mf < 2; ++mf)
#pragma unroll
            for (int nf = 0; nf < NF; ++nf)
                acc[mf][nf] = __builtin_amdgcn_mfma_f32_16x16x32_bf16(af[mf], bf_[nf], acc[mf][nf], 0, 0, 0);
    };

    stage_A16(0, 0);
    stage_B(0, 0);
    __syncthreads();

    int buf = 0;
    for (int ks = 0; ks < NK; ++ks) {
        const int kk = (ks + 1) * BK;
        if (ks + 1 < NK) {
            stage_A16(buf ^ 1, kk);
            stage_B(buf ^ 1, kk);
        }
        compute(buf);
        __syncthreads();
        buf ^= 1;
    }

#pragma unroll
    for (int mf = 0; mf < 2; ++mf) {
#pragma unroll
        for (int nf = 0; nf < NF; ++nf) {
            int col = bn0 + wn * (BN / 2) + nf * 16 + lr;
#pragma unroll
            for (int p = 0; p < 4; ++p) {
                int row = bm0 + wm * 32 + mf * 16 + lg * 4 + p;
                if (row < M)
                    Cp[(size_t)row * Nc + col] = f2fp8(acc[mf][nf][p]);
            }
        }
    }

    if constexpr (NF == 4) {
        float cs[4], cd[4];
#pragma unroll
        for (int nf = 0; nf < 4; ++nf) {
            int col = bn0 + wn * 64 + nf * 16 + lr;
            cs[nf] = asv[col];
            cd[nf] = adv[col];
        }
        const int hb = (bn0 >> 5) + wn * 2;
#pragma unroll
        for (int mf = 0; mf < 2; ++mf) {
#pragma unroll
            for (int p = 0; p < 4; ++p) {
                float sA = acc[mf][0][p] * cs[0] + acc[mf][1][p] * cs[1];
                float sB = acc[mf][2][p] * cs[2] + acc[mf][3][p] * cs[3];
                float dA = acc[mf][0][p] * cd[0] + acc[mf][1][p] * cd[1];
                float dB = acc[mf][2][p] * cd[2] + acc[mf][3][p] * cd[3];
#pragma unroll
                for (int off = 1; off < 16; off <<= 1) {
                    sA += __shfl_xor(sA, off);
                    sB += __shfl_xor(sB, off);
                    dA += __shfl_xor(dA, off);
                    dB += __shfl_xor(dB, off);
                }
                int row = bm0 + wm * 32 + mf * 16 + lg * 4 + p;
                if (lr == 0 && row < M) {
                    asrc[row * 8 + hb] = sA;
                    asrc[row * 8 + hb + 1] = sB;
                    adst[row * 8 + hb] = dA;
                    adst[row * 8 + hb + 1] = dB;
                }
            }
        }
    }
}

// ---------------- GEMM layer 2 (K=256, Nc=64), BM=64, bf16 store + fused alpha2 ----------------
__global__ __launch_bounds__(256) void k_gemm2(const ushort* __restrict__ Ap,
                                               const ushort* __restrict__ BT,
                                               ushort* __restrict__ Cp,
                                               const float* __restrict__ asv,
                                               const float* __restrict__ adv,
                                               float* __restrict__ asrc,
                                               float* __restrict__ adst, int M) {
    constexpr int K = 256, BM = 64, BK = 32;
    constexpr int NK = K / BK;
    constexpr int BU = 64 * BK / 8;
    constexpr int AU = BM * BK / 8;
    constexpr int TU = AU + BU;
    __shared__ __align__(16) ushort lds[2][TU * 8];

    const int t = threadIdx.x;
    const int wid = t >> 6, lane = t & 63;
    const int lr = lane & 15, lg = lane >> 4;
    const int bm0 = blockIdx.x * BM;

    int a_off0, b_off[4];
    {
        int row = wid * 16 + lr;
        a_off0 = row * 64 + ((lg ^ ((row >> 1) & 3)) << 4);
    }
#pragma unroll
    for (int nf = 0; nf < 4; ++nf) {
        int col = nf * 16 + lr;
        b_off[nf] = AU * 16 + col * 64 + ((lg ^ ((col >> 1) & 3)) << 4);
    }

    f32x4 acc[4];
#pragma unroll
    for (int nf = 0; nf < 4; ++nf) acc[nf] = f32x4{0.f, 0.f, 0.f, 0.f};

    auto stage_B = [&](int buf, int kk) {
        int u = t;
        int col = u >> 2;
        int g = (u & 3) ^ ((col >> 1) & 3);
        const ushort* src = BT + (size_t)col * K + kk + g * 8;
        gload16(src, &lds[buf][(AU + u) * 8]);
    };
    auto stage_A = [&](int buf, int kk) {
        int u = t;
        int row = u >> 2;
        int g = (u & 3) ^ ((row >> 1) & 3);
        int grow = bm0 + row;
        if (grow >= M) grow = M - 1;
        const ushort* src = Ap + (size_t)grow * K + kk + g * 8;
        gload16(src, &lds[buf][u * 8]);
    };
    auto compute = [&](int buf) {
        const char* base = (const char*)lds[buf];
        short8 af = *(const short8*)(base + a_off0);
        short8 bf_[4];
#pragma unroll
        for (int nf = 0; nf < 4; ++nf) bf_[nf] = *(const short8*)(base + b_off[nf]);
#pragma unroll
        for (int nf = 0; nf < 4; ++nf)
            acc[nf] = __builtin_amdgcn_mfma_f32_16x16x32_bf16(af, bf_[nf], acc[nf], 0, 0, 0);
    };

    stage_A(0, 0);
    stage_B(0, 0);
    __syncthreads();
    int buf = 0;
    for (int ks = 0; ks < NK; ++ks) {
        if (ks + 1 < NK) {
            stage_A(buf ^ 1, (ks + 1) * BK);
            stage_B(buf ^ 1, (ks + 1) * BK);
        }
        compute(buf);
        __syncthreads();
        buf ^= 1;
    }

    float cs[4], cd[4];
#pragma unroll
    for (int nf = 0; nf < 4; ++nf) {
        cs[nf] = asv[nf * 16 + lr];
        cd[nf] = adv[nf * 16 + lr];
    }
#pragma unroll
    for (int p = 0; p < 4; ++p) {
        int row = bm0 + wid * 16 + lg * 4 + p;
#pragma unroll
        for (int nf = 0; nf < 4; ++nf) {
            if (row < M)
                Cp[(size_t)row * 64 + nf * 16 + lr] = f2bf(acc[nf][p]);
        }
        float sA = acc[0][p] * cs[0] + acc[1][p] * cs[1] +
                   acc[2][p] * cs[2] + acc[3][p] * cs[3];
        float dA = acc[0][p] * cd[0] + acc[1][p] * cd[1] +
                   acc[2][p] * cd[2] + acc[3][p] * cd[3];
#pragma unroll
        for (int off = 1; off < 16; off <<= 1) {
            sA += __shfl_xor(sA, off);
            dA += __shfl_xor(dA, off);
        }
        if (lr == 0 && row < M) {
            asrc[row] = sA;
            adst[row] = dA;
        }
    }
}

// ---------------- fused softmax+aggregation, layers 0/1: h gathered as fp8 e4m3 ----------------
#define MAXW 96
__global__ __launch_bounds__(128) void k_agg(const unsigned char* __restrict__ h8,
                                             const float* __restrict__ asrc,
                                             const float* __restrict__ adst,
                                             const int* __restrict__ rowptr,
                                             const int* __restrict__ col,
                                             const float* __restrict__ bias,
                                             ushort* __restrict__ anext, int n) {
    __shared__ float wl[2][MAXW * 8];
    int wid = threadIdx.x >> 6;
    int lane = threadIdx.x & 63;
    int node = blockIdx.x * 2 + wid;
    if (node >= n) return;
    int beg = rowptr[node], end = rowptr[node + 1];
    int deg = end - beg;
    int hd = lane >> 3;
    int eo = lane & 7;
    float ad = adst[node * 8 + hd];
    float* wp = wl[wid];

    float sacc = 0.f;
    for (int jb = eo; jb < deg; jb += 8) {
        int s = col[beg + jb];
        float w = __expf(lrelu(asrc[s * 8 + hd] + ad));
        if (jb < MAXW) wp[jb * 8 + hd] = w;
        sacc += w;
    }
    sacc += __shfl_xor(sacc, 1);
    sacc += __shfl_xor(sacc, 2);
    sacc += __shfl_xor(sacc, 4);
    float inv = 1.f / (sacc + 1e-16f);

    int nl = (deg < MAXW) ? deg : MAXW;
    float a0 = 0.f, a1 = 0.f, a2 = 0.f, a3 = 0.f;
    int jb = 0;
    for (; jb + 8 <= nl; jb += 8) {
        int sv[8];
#pragma unroll
        for (int i = 0; i < 8; ++i) sv[i] = col[beg + jb + i];
        unsigned gv[8];
#pragma unroll
        for (int i = 0; i < 8; ++i) gv[i] = *(const unsigned*)(h8 + (size_t)sv[i] * 256 + lane * 4);
        float wv[8];
#pragma unroll
        for (int i = 0; i < 8; ++i) wv[i] = wp[(jb + i) * 8 + hd];
#pragma unroll
        for (int i = 0; i < 8; ++i) {
            a0 += wv[i] * __builtin_amdgcn_cvt_f32_fp8(gv[i], 0);
            a1 += wv[i] * __builtin_amdgcn_cvt_f32_fp8(gv[i], 1);
            a2 += wv[i] * __builtin_amdgcn_cvt_f32_fp8(gv[i], 2);
            a3 += wv[i] * __builtin_amdgcn_cvt_f32_fp8(gv[i], 3);
        }
    }
    for (; jb < nl; ++jb) {
        int s = col[beg + jb];
        unsigned g = *(const unsigned*)(h8 + (size_t)s * 256 + lane * 4);
        float w = wp[jb * 8 + hd];
        a0 += w * __builtin_amdgcn_cvt_f32_fp8(g, 0);
        a1 += w * __builtin_amdgcn_cvt_f32_fp8(g, 1);
        a2 += w * __builtin_amdgcn_cvt_f32_fp8(g, 2);
        a3 += w * __builtin_amdgcn_cvt_f32_fp8(g, 3);
    }
    for (; jb < deg; ++jb) {
        int s = col[beg + jb];
        unsigned g = *(const unsigned*)(h8 + (size_t)s * 256 + lane * 4);
        float w = __expf(lrelu(asrc[s * 8 + hd] + ad));
        a0 += w * __builtin_amdgcn_cvt_f32_fp8(g, 0);
        a1 += w * __builtin_amdgcn_cvt_f32_fp8(g, 1);
        a2 += w * __builtin_amdgcn_cvt_f32_fp8(g, 2);
        a3 += w * __builtin_amdgcn_cvt_f32_fp8(g, 3);
    }
    f32x4 bv = *(const f32x4*)(bias + lane * 4);
    float v0 = a0 * inv + bv[0];
    float v1 = a1 * inv + bv[1];
    float v2 = a2 * inv + bv[2];
    float v3 = a3 * inv + bv[3];
    v0 = (v0 > 0.f) ? v0 : expm1f(v0);
    v1 = (v1 > 0.f) ? v1 : expm1f(v1);
    v2 = (v2 > 0.f) ? v2 : expm1f(v2);
    v3 = (v3 > 0.f) ? v3 : expm1f(v3);
    us4 o;
    o[0] = f2bf(v0); o[1] = f2bf(v1); o[2] = f2bf(v2); o[3] = f2bf(v3);
    *(us4*)(anext + (size_t)node * 256 + lane * 4) = o;
}

// ---------------- fused layer 2 + bias + log_softmax ----------------
__global__ __launch_bounds__(128) void k_agg2(const ushort* __restrict__ h2,
                                              const float* __restrict__ asrc,
                                              const float* __restrict__ adst,
                                              const int* __restrict__ rowptr,
                                              const int* __restrict__ col,
                                              const float* __restrict__ bias,
                                              float* __restrict__ out, int n) {
    int wid = threadIdx.x >> 6;
    int lane = threadIdx.x & 63;
    int node = blockIdx.x * 2 + wid;
    if (node >= n) return;
    int beg = rowptr[node], end = rowptr[node + 1];
    int deg = end - beg;
    float ad = adst[node];
    int g = lane >> 3;
    int ch = (lane & 7) * 8;

    f32x2 acc2[4];
#pragma unroll
    for (int i = 0; i < 4; ++i) acc2[i] = f32x2{0.f, 0.f};
    float ssum = 0.f;
    for (int p = 0; p < deg; p += 8) {
        int jb = p + g;
        float w = 0.f;
        uint4 gv = {0u, 0u, 0u, 0u};
        if (jb < deg) {
            int s = col[beg + jb];
            gv = *(const uint4*)(h2 + (size_t)s * 64 + ch);
            w = __expf(lrelu(asrc[s] + ad));
        }
        ssum += w;
        f32x2 w2 = {w, w};
        f32x2 p0 = {__uint_as_float(gv.x << 16), __uint_as_float(gv.x & 0xFFFF0000u)};
        f32x2 p1 = {__uint_as_float(gv.y << 16), __uint_as_float(gv.y & 0xFFFF0000u)};
        f32x2 p2 = {__uint_as_float(gv.z << 16), __uint_as_float(gv.z & 0xFFFF0000u)};
        f32x2 p3 = {__uint_as_float(gv.w << 16), __uint_as_float(gv.w & 0xFFFF0000u)};
        acc2[0] += w2 * p0;
        acc2[1] += w2 * p1;
        acc2[2] += w2 * p2;
        acc2[3] += w2 * p3;
    }
    float v[8];
#pragma unroll
    for (int i = 0; i < 4; ++i) { v[2 * i] = acc2[i].x; v[2 * i + 1] = acc2[i].y; }
#pragma unroll
    for (int off = 8; off < 64; off <<= 1) {
        ssum += __shfl_xor(ssum, off);
#pragma unroll
        for (int i = 0; i < 8; ++i) v[i] += __shfl_xor(v[i], off);
    }
    float inv = 1.f / (ssum + 1e-16f);
#pragma unroll
    for (int i = 0; i < 8; ++i) v[i] = v[i] * inv + bias[ch + i];
    float mx = v[0];
#pragma unroll
    for (int i = 1; i < 8; ++i) mx = fmaxf(mx, v[i]);
    mx = fmaxf(mx, __shfl_xor(mx, 1));
    mx = fmaxf(mx, __shfl_xor(mx, 2));
    mx = fmaxf(mx, __shfl_xor(mx, 4));
    float se = 0.f;
#pragma unroll
    for (int i = 0; i < 8; ++i) se += __expf(v[i] - mx);
    se += __shfl_xor(se, 1);
    se += __shfl_xor(se, 2);
    se += __shfl_xor(se, 4);
    float ls = mx + logf(se);
    if (g == 0) {
        f32x4 o0, o1;
#pragma unroll
        for (int i = 0; i < 4; ++i) { o0[i] = v[i] - ls; o1[i] = v[4 + i] - ls; }
        *(f32x4*)(out + (size_t)node * 64 + ch) = o0;
        *(f32x4*)(out + (size_t)node * 64 + ch + 4) = o1;
    }
}

extern "C" void kernel_launch(void* const* d_in, const int* in_sizes, int n_in,
                              void* d_out, int out_size, void* d_ws, size_t ws_size,
                              hipStream_t stream) {
    const float* x   = (const float*)d_in[0];
    const int*   ei  = (const int*)d_in[1];
    const float* W0  = (const float*)d_in[2];
    const float* as0 = (const float*)d_in[3];
    const float* ad0 = (const float*)d_in[4];
    const float* b0  = (const float*)d_in[5];
    const float* W1  = (const float*)d_in[6];
    const float* as1 = (const float*)d_in[7];
    const float* ad1 = (const float*)d_in[8];
    const float* b1  = (const float*)d_in[9];
    const float* W2  = (const float*)d_in[10];
    const float* as2 = (const float*)d_in[11];
    const float* ad2 = (const float*)d_in[12];
    const float* b2  = (const float*)d_in[13];
    float* out = (float*)d_out;

    const int N = in_sizes[0] / 512;   // 50000
    const int E = in_sizes[1] / 2;     // 800000
    const int ETOT = E + N;

    char* ws = (char*)d_ws;
    size_t off = 0;
    auto alloc = [&](size_t bytes) -> void* {
        off = (off + 255) & ~(size_t)255;
        void* p = ws + off;
        off += bytes;
        return p;
    };
    int* rowptr = (int*)alloc((size_t)(N + 1) * 4);
    int* cursor = (int*)alloc((size_t)N * 4);
    int* deg    = (int*)alloc((size_t)N * 4);
    int* bsum   = (int*)alloc(1024);
    int* colb   = (int*)alloc((size_t)ETOT * 4);
    ushort* WT0 = (ushort*)alloc((size_t)256 * 512 * 2);
    ushort* WT1 = (ushort*)alloc((size_t)256 * 256 * 2);
    ushort* WT2 = (ushort*)alloc((size_t)64 * 256 * 2);
    unsigned char* h8 = (unsigned char*)alloc((size_t)N * 256);  // fp8 h
    ushort* abf = (ushort*)alloc((size_t)N * 256 * 2);
    float* asrc = (float*)alloc((size_t)N * 8 * 4);
    float* adst = (float*)alloc((size_t)N * 8 * 4);
    // aliases (lifetimes disjoint)
    ushort* h2   = (ushort*)h8;
    float* asrc2 = asrc;
    float* adst2 = adst;

    const int nblk = (N + 255) / 256;        // 196
    const int nhb  = (E + 1023) / 1024;      // 782 hist blocks
    const int nsb  = (ETOT + 1023) / 1024;   // 831 scatter blocks

    // deg zeroing, then fat: weight cvt || histogram
    hipMemsetAsync(deg, 0, (size_t)N * 4, stream);
    k_wh<<<832 + nhb, 256, 0, stream>>>(W0, WT0, W1, WT1, W2, WT2, ei + E, deg, E, nhb);

    // scans
    k_scanA<<<nblk, 256, 0, stream>>>(deg, bsum, N);
    k_scanC<<<nblk, 256, 0, stream>>>(deg, bsum, rowptr, cursor, N, ETOT, nblk);

    const int gblk = (N + 63) / 64;          // 782
    const int ngb  = 2 * gblk;               // 1564 gemm blocks
    const int ablk = (N + 1) / 2;            // 25000

    // fat: scatter || gemm layer 0, interleaved roles (bid&3==3 -> scatter)
    const int fatT = 4 * nsb;                // 3324 (covers 831 scatter; >=1564 gemm slots)
    k_g0s<<<fatT, 256, 0, stream>>>(x, WT0, h8, as0, ad0, asrc, adst, N,
                                    ei, cursor, colb, E, nsb, ngb);
    k_agg<<<ablk, 128, 0, stream>>>(h8, asrc, adst, rowptr, colb, b0, abf, N);

    // layer 1
    k_gemm<256, 128><<<dim3(gblk, 2), 256, 0, stream>>>(abf, WT1, h8, as1, ad1, asrc, adst, N);
    k_agg<<<ablk, 128, 0, stream>>>(h8, asrc, adst, rowptr, colb, b1, abf, N);

    // layer 2 (gemm + fused alpha2)
    k_gemm2<<<gblk, 256, 0, stream>>>(abf, WT2, h2, as2, ad2, asrc2, adst2, N);
    k_agg2<<<ablk, 128, 0, stream>>>(h2, asrc2, adst2, rowptr, colb, b2, out, N);
}